// Round 8
// baseline (256.795 us; speedup 1.0000x reference)
//
#include <hip/hip_runtime.h>

#define BB 4
#define CC 256
#define DD 32
#define SS 4096

typedef __bf16 bf16;
typedef __bf16 bf16x8 __attribute__((ext_vector_type(8)));
typedef __bf16 bf16x4 __attribute__((ext_vector_type(4)));
typedef float f32x4 __attribute__((ext_vector_type(4)));
typedef unsigned int u32;
typedef unsigned short u16;

// barrier that drains ONLY LDS (lgkm): global prefetches stay in flight.
#define BAR() asm volatile("s_waitcnt lgkmcnt(0)\n\ts_barrier" ::: "memory")

// workspace layout (bf16 elements):
//  q:  [2][BB][SS][DD]  off 0         (pos-major, 32 d inner)
//  k:  [2][BB][SS][DD]  off 1048576
//  v:  [2][BB][CC][SS]  off 2097152   (c-major, pos inner)
//  wb: [320][CC]        off 10485760  (bf16 Wq|Wk|Wv stacked)
#define Q_OFF  0
#define K_OFF  1048576
#define V_OFF  2097152
#define WB_OFF 10485760

static __device__ __forceinline__ u32 pack2(float lo, float hi) {
    bf16 a = (bf16)lo, b = (bf16)hi;
    u16 ua = __builtin_bit_cast(u16, a), ub = __builtin_bit_cast(u16, b);
    return (u32)ua | ((u32)ub << 16);
}

// ------------------------------------------------- W fp32 -> bf16 [320][256]
__global__ __launch_bounds__(256) void convert_w_kernel(
    const float* __restrict__ Wq, const float* __restrict__ Wk,
    const float* __restrict__ Wv, bf16* __restrict__ wb)
{
    const int gid = blockIdx.x*256 + threadIdx.x;    // 40 blocks -> 10240
    const int idx = gid*8;
    const int o = idx >> 8, cc = idx & 255;
    const float* row = (o < 32) ? (Wq + (size_t)o*CC)
                     : (o < 64) ? (Wk + (size_t)(o-32)*CC)
                                : (Wv + (size_t)(o-64)*CC);
    const float4 a = *(const float4*)(row + cc);
    const float4 c = *(const float4*)(row + cc + 4);
    bf16x8 pk;
    pk[0]=(bf16)a.x; pk[1]=(bf16)a.y; pk[2]=(bf16)a.z; pk[3]=(bf16)a.w;
    pk[4]=(bf16)c.x; pk[5]=(bf16)c.y; pk[6]=(bf16)c.z; pk[7]=(bf16)c.w;
    *(bf16x8*)(wb + idx) = pk;
}

// ------------------------------------------------- fused q,k,v projection (MFMA)
__global__ __launch_bounds__(256, 2) void proj_all_kernel(
    const float* __restrict__ x, const float* __restrict__ y,
    const bf16* __restrict__ wb,
    const float* __restrict__ bq, const float* __restrict__ bk,
    const float* __restrict__ bv,
    bf16* __restrict__ qout, bf16* __restrict__ kout, bf16* __restrict__ vout)
{
    // xT: [2][64 pos][40 bf16] (row 80 B, 16B-aligned)
    __shared__ __align__(16) char smem[2*5120];
    bf16* xT  = (bf16*)smem;
    u32*  xTw = (u32*)smem;

    const int t    = threadIdx.x;
    const int lane = t & 63;
    const int w    = t >> 6;
    const int ln   = lane & 15;
    const int quad = lane >> 4;

    const int bid  = blockIdx.x;
    const int dirb = bid & 7;
    const int src  = dirb >> 2;
    const int b    = dirb & 3;
    const int i0   = (bid >> 3) * 64;
    const float* in = src ? y : x;
    const float* xbase = in + (size_t)b*CC*SS + i0;

    const int cp = t >> 4;            // cc-pair 0..15 -> cc {2cp, 2cp+1}
    const int pq = (t & 15) * 4;      // pos 0..60

    float bias[5];
    #pragma unroll
    for (int nbl = 0; nbl < 5; ++nbl) {
        const int o = 80*w + nbl*16 + ln;
        bias[nbl] = (o < 32) ? bq[o] : (o < 64) ? bk[o-32] : bv[o-64];
    }
    f32x4 acc[4][5];
    #pragma unroll
    for (int mb = 0; mb < 4; ++mb)
        #pragma unroll
        for (int nbl = 0; nbl < 5; ++nbl)
            acc[mb][nbl] = (f32x4){bias[nbl], bias[nbl], bias[nbl], bias[nbl]};

    const bf16* wrow = wb + (size_t)(80*w + ln)*CC + quad*8;
    bf16x8 bf[5];
    #pragma unroll
    for (int nbl = 0; nbl < 5; ++nbl)
        bf[nbl] = *(const bf16x8*)(wrow + (size_t)nbl*16*CC);

    // stage chunk 0 into buf0
    {
        const float* r0 = xbase + (size_t)(2*cp)*SS + pq;
        const float4 a0 = *(const float4*)r0;
        const float4 a1 = *(const float4*)(r0 + SS);
        xTw[(pq+0)*20 + cp] = pack2(a0.x, a1.x);
        xTw[(pq+1)*20 + cp] = pack2(a0.y, a1.y);
        xTw[(pq+2)*20 + cp] = pack2(a0.z, a1.z);
        xTw[(pq+3)*20 + cp] = pack2(a0.w, a1.w);
    }
    // prefetch chunk 1 into regs
    float4 a0, a1;
    {
        const float* r1 = xbase + (size_t)(32 + 2*cp)*SS + pq;
        a0 = *(const float4*)r1;
        a1 = *(const float4*)(r1 + SS);
    }
    BAR();

    for (int n = 0; n < 8; ++n) {
        bf16x8 af[4];
        #pragma unroll
        for (int mb = 0; mb < 4; ++mb)
            af[mb] = *(const bf16x8*)(xT + (n&1)*2560 + (mb*16 + ln)*40 + quad*8);
        if (n < 7) {
            u32* dst = xTw + ((n+1)&1)*1280;
            dst[(pq+0)*20 + cp] = pack2(a0.x, a1.x);
            dst[(pq+1)*20 + cp] = pack2(a0.y, a1.y);
            dst[(pq+2)*20 + cp] = pack2(a0.z, a1.z);
            dst[(pq+3)*20 + cp] = pack2(a0.w, a1.w);
        }
        {
            const int cc2 = ((n+2)*32) & 255;
            const float* r2 = xbase + (size_t)(cc2 + 2*cp)*SS + pq;
            a0 = *(const float4*)r2;
            a1 = *(const float4*)(r2 + SS);
        }
        #pragma unroll
        for (int mb = 0; mb < 4; ++mb)
            #pragma unroll
            for (int nbl = 0; nbl < 5; ++nbl)
                acc[mb][nbl] = __builtin_amdgcn_mfma_f32_16x16x32_bf16(
                                   af[mb], bf[nbl], acc[mb][nbl], 0, 0, 0);
        const int ccn = ((n+1)*32) & 255;
        #pragma unroll
        for (int nbl = 0; nbl < 5; ++nbl)
            bf[nbl] = *(const bf16x8*)(wrow + (size_t)nbl*16*CC + ccn);
        BAR();
    }

    bf16* qo = qout + (size_t)(src*BB + b)*SS*DD;
    bf16* ko = kout + (size_t)(src*BB + b)*SS*DD;
    bf16* vo = vout + (size_t)(src*BB + b)*CC*SS;
    #pragma unroll
    for (int nbl = 0; nbl < 5; ++nbl) {
        const int o = 80*w + nbl*16 + ln;
        if (o < 32) {
            #pragma unroll
            for (int mb = 0; mb < 4; ++mb)
                #pragma unroll
                for (int r = 0; r < 4; ++r)
                    qo[(size_t)(i0 + mb*16 + quad*4 + r)*DD + o] = (bf16)acc[mb][nbl][r];
        } else if (o < 64) {
            #pragma unroll
            for (int mb = 0; mb < 4; ++mb)
                #pragma unroll
                for (int r = 0; r < 4; ++r)
                    ko[(size_t)(i0 + mb*16 + quad*4 + r)*DD + (o-32)] = (bf16)acc[mb][nbl][r];
        } else {
            const int c = o - 64;
            #pragma unroll
            for (int mb = 0; mb < 4; ++mb) {
                bf16x4 pk;
                #pragma unroll
                for (int r = 0; r < 4; ++r) pk[r] = (bf16)acc[mb][nbl][r];
                *(bf16x4*)(vo + (size_t)c*SS + i0 + mb*16 + quad*4) = pk;
            }
        }
    }
}

// ------------------------------------------------- attention (pipelined, S^T)
// Identical math to round 7; scheduling changes only:
//  - lgkm-only barrier (V/K prefetch stays in flight across it)
//  - vf double-buffered; V(n+1) issued immediately post-barrier
#define SM_M 16.0f

#define ATTN_ITER(NN, VCUR, VNXT, PRBUF, PWBUF)                               \
  {                                                                           \
    BAR();                                                                    \
    const int jn1 = ((NN + 1) << 6) & (SS - 1);                               \
    if ((NN) < 63) {                                                          \
      _Pragma("unroll")                                                       \
      for (int ks = 0; ks < 2; ++ks)                                          \
        _Pragma("unroll")                                                     \
        for (int cb = 0; cb < 4; ++cb)                                        \
          VNXT[ks][cb] = *(const bf16x8*)(vptr[cb] + jn1 + ks*32);            \
    }                                                                         \
    f32x4 s[4];                                                               \
    if ((NN) < 63) {                                                          \
      _Pragma("unroll")                                                       \
      for (int nb = 0; nb < 4; ++nb)                                          \
        s[nb] = __builtin_amdgcn_mfma_f32_16x16x32_bf16(kf[nb], b_q,          \
                    (f32x4){0.f,0.f,0.f,0.f}, 0, 0, 0);                       \
      const int j2 = ((NN + 2) << 6) & (SS - 1);                              \
      _Pragma("unroll")                                                       \
      for (int nb = 0; nb < 4; ++nb)                                          \
        kf[nb] = *(const bf16x8*)(kbase + (size_t)(j2 + nb*16)*DD);           \
    }                                                                         \
    _Pragma("unroll")                                                         \
    for (int ks = 0; ks < 2; ++ks) {                                          \
      bf16x8 ap[4];                                                           \
      _Pragma("unroll")                                                       \
      for (int qb = 0; qb < 4; ++qb)                                          \
        ap[qb] = *(const bf16x8*)(PRBUF + (qb*16 + ln)*72 + ks*32 + quad*8);  \
      _Pragma("unroll")                                                       \
      for (int qb = 0; qb < 4; ++qb)                                          \
        _Pragma("unroll")                                                     \
        for (int cb = 0; cb < 4; ++cb)                                        \
          o[qb][cb] = __builtin_amdgcn_mfma_f32_16x16x32_bf16(                \
                          ap[qb], VCUR[ks][cb], o[qb][cb], 0, 0, 0);          \
    }                                                                         \
    if ((NN) < 63) {                                                          \
      _Pragma("unroll")                                                       \
      for (int nb = 0; nb < 4; ++nb) {                                        \
        bf16x4 pk;                                                            \
        _Pragma("unroll")                                                     \
        for (int r = 0; r < 4; ++r) {                                         \
          const float e = __expf(fminf(s[nb][r] - SM_M, 60.0f));              \
          lp += e;                                                            \
          pk[r] = (bf16)e;                                                    \
        }                                                                     \
        *(bf16x4*)(PWBUF + (w*16 + ln)*72 + nb*16 + quad*4) = pk;             \
      }                                                                       \
    }                                                                         \
  }

__global__ __launch_bounds__(256, 2) void attn_kernel(
    const bf16* __restrict__ qg, const bf16* __restrict__ kg,
    const bf16* __restrict__ vg, float* __restrict__ out)
{
    __shared__ __align__(16) char smem[18688];
    bf16*  p_s = (bf16*)smem;               // [2][64][72]
    float* l_s = (float*)(smem + 18432);    // [64]

    const int t    = threadIdx.x;
    const int lane = t & 63;
    const int w    = t >> 6;
    const int ln   = lane & 15;
    const int quad = lane >> 4;

    const int bid  = blockIdx.x;
    const int dirb = bid & 7;
    const int dir  = dirb >> 2;
    const int b    = dirb & 3;
    const int i0   = (bid >> 3) * 64;

    const bf16* q = qg + ((size_t)dir*BB + b)*SS*DD + (size_t)i0*DD;
    const bf16* k = kg + ((size_t)(1-dir)*BB + b)*SS*DD;
    const bf16* v = vg + ((size_t)(1-dir)*BB + b)*CC*SS;
    float* op = out + ((size_t)dir*BB + b)*CC*SS;

    // Q as B-frag: B[n=q(ln)][k=d(quad*8+)]  (wave's 16 queries)
    const bf16x8 b_q = *(const bf16x8*)(q + (size_t)(w*16 + ln)*DD + quad*8);
    const bf16* kbase = k + (size_t)ln*DD + quad*8;
    const bf16* vptr[4];
    #pragma unroll
    for (int cb = 0; cb < 4; ++cb)
        vptr[cb] = v + (size_t)(w*64 + cb*16 + ln)*SS + quad*8;

    f32x4 o[4][4];
    #pragma unroll
    for (int qb = 0; qb < 4; ++qb)
        #pragma unroll
        for (int cb = 0; cb < 4; ++cb) o[qb][cb] = (f32x4){0.f,0.f,0.f,0.f};
    float lp = 0.f;

    bf16x8 kf[4], vfA[2][4], vfB[2][4];
    #pragma unroll
    for (int nb = 0; nb < 4; ++nb)
        kf[nb] = *(const bf16x8*)(kbase + (size_t)(nb*16)*DD);
    #pragma unroll
    for (int ks = 0; ks < 2; ++ks)
        #pragma unroll
        for (int cb = 0; cb < 4; ++cb)
            vfA[ks][cb] = *(const bf16x8*)(vptr[cb] + ks*32);

    bf16* pbuf0 = p_s;
    bf16* pbuf1 = p_s + 4608;

    // prologue: S^T(0) + softmax(0) -> buf0
    {
        f32x4 s[4];
        #pragma unroll
        for (int nb = 0; nb < 4; ++nb)
            s[nb] = __builtin_amdgcn_mfma_f32_16x16x32_bf16(
                        kf[nb], b_q, (f32x4){0.f,0.f,0.f,0.f}, 0, 0, 0);
        #pragma unroll
        for (int nb = 0; nb < 4; ++nb)
            kf[nb] = *(const bf16x8*)(kbase + (size_t)(64 + nb*16)*DD);
        #pragma unroll
        for (int nb = 0; nb < 4; ++nb) {
            bf16x4 pk;
            #pragma unroll
            for (int r = 0; r < 4; ++r) {
                const float e = __expf(fminf(s[nb][r] - SM_M, 60.0f));
                lp += e;
                pk[r] = (bf16)e;
            }
            *(bf16x4*)(pbuf0 + (w*16 + ln)*72 + nb*16 + quad*4) = pk;
        }
    }

    for (int n = 0; n < 64; n += 2) {
        ATTN_ITER(n,     vfA, vfB, pbuf0, pbuf1)
        ATTN_ITER(n + 1, vfB, vfA, pbuf1, pbuf0)
    }

    // l: lane covers keys {*, nb*16+quad*4+r} for query w*16+ln -> reduce quads
    lp += __shfl_xor(lp, 16);
    lp += __shfl_xor(lp, 32);
    if (lane < 16) l_s[w*16 + ln] = lp;
    __syncthreads();

    // epilogue: normalize + direct coalesced stores
    #pragma unroll
    for (int qb = 0; qb < 4; ++qb) {
        const f32x4 lq = *(const f32x4*)(l_s + qb*16 + quad*4);
        const float ri0 = 1.0f/lq[0], ri1 = 1.0f/lq[1], ri2 = 1.0f/lq[2], ri3 = 1.0f/lq[3];
        #pragma unroll
        for (int cb = 0; cb < 4; ++cb) {
            const int c = w*64 + cb*16 + ln;
            float4 val = make_float4(o[qb][cb][0]*ri0, o[qb][cb][1]*ri1,
                                     o[qb][cb][2]*ri2, o[qb][cb][3]*ri3);
            *(float4*)(op + (size_t)c*SS + i0 + qb*16 + quad*4) = val;
        }
    }
}

// ------------------------------------------------- launch
extern "C" void kernel_launch(void* const* d_in, const int* in_sizes, int n_in,
                              void* d_out, int out_size, void* d_ws, size_t ws_size,
                              hipStream_t stream)
{
    const float* x  = (const float*)d_in[0];
    const float* y  = (const float*)d_in[1];
    const float* Wq = (const float*)d_in[2];
    const float* bq = (const float*)d_in[3];
    const float* Wk = (const float*)d_in[4];
    const float* bk = (const float*)d_in[5];
    const float* Wv = (const float*)d_in[6];
    const float* bv = (const float*)d_in[7];
    float* out = (float*)d_out;
    bf16* ws   = (bf16*)d_ws;

    bf16* qw = ws + Q_OFF;
    bf16* kw = ws + K_OFF;
    bf16* vw = ws + V_OFF;
    bf16* wb = ws + WB_OFF;

    convert_w_kernel<<<40,  256, 0, stream>>>(Wq, Wk, Wv, wb);
    proj_all_kernel <<<512, 256, 0, stream>>>(x, y, wb, bq, bk, bv, qw, kw, vw);
    attn_kernel     <<<512, 256, 0, stream>>>(qw, kw, vw, out);
}